// Round 4
// baseline (2710.604 us; speedup 1.0000x reference)
//
#include <hip/hip_runtime.h>

typedef __attribute__((ext_vector_type(8))) short short8;
typedef __attribute__((ext_vector_type(4))) float f32x4;
typedef __attribute__((ext_vector_type(8))) unsigned short u16x8;
typedef unsigned short u16;

#define V_SIZE 32000
#define D_MODEL 1024
#define HFF 4096
#define NHEAD 16
#define HDIM 64
#define NLAYER 4
#define BT 4096   // B*T tokens
#define TSEQ 2048
#define QKV_STRIDE 3072
#define GU_STRIDE 8192

__device__ __forceinline__ u16 f2bf(float f) {
  union { float f; unsigned u; } v; v.f = f;
  unsigned r = v.u + 0x7fffu + ((v.u >> 16) & 1u);
  return (u16)(r >> 16);
}
__device__ __forceinline__ float bf2f(u16 h) {
  union { unsigned u; float f; } v; v.u = ((unsigned)h) << 16;
  return v.f;
}

__device__ __forceinline__ void gload_lds16(const void* g, void* l) {
  __builtin_amdgcn_global_load_lds((__attribute__((address_space(1))) void*)g,
                                   (__attribute__((address_space(3))) void*)l, 16, 0, 0);
}

// ---------------- elementwise / small kernels ----------------

__global__ void rope_table_kernel(float* __restrict__ cosb, float* __restrict__ sinb) {
  int i = blockIdx.x * 256 + threadIdx.x;       // 2048*32 = 65536 items
  int t = i >> 5, fi = i & 31;
  float freq = exp2f(-(2.0f * (float)fi / 64.0f) * log2f(10000.0f));
  float ang = (float)t * freq;
  cosb[i] = cosf(ang);
  sinb[i] = sinf(ang);
}

__global__ void convert_bf16_kernel(const float* __restrict__ src, u16* __restrict__ dst, long n8) {
  long i = (long)blockIdx.x * 256 + threadIdx.x;
  long stride = (long)gridDim.x * 256;
  for (; i < n8; i += stride) {
    const float4* s = (const float4*)(src + i * 8);
    float4 a = s[0], b = s[1];
    u16x8 r;
    r[0] = f2bf(a.x); r[1] = f2bf(a.y); r[2] = f2bf(a.z); r[3] = f2bf(a.w);
    r[4] = f2bf(b.x); r[5] = f2bf(b.y); r[6] = f2bf(b.z); r[7] = f2bf(b.w);
    *(u16x8*)(dst + i * 8) = r;
  }
}

// src [R][C] fp32 -> dst bf16 at dst[(c*rowMul+rowAdd)*R + r], batched over blockIdx.z
__global__ __launch_bounds__(256) void transpose_bf16_kernel(const float* __restrict__ src0,
                                                             u16* __restrict__ dst0, int R, int C,
                                                             long srcStride, long dstStride,
                                                             int rowMul, int rowAdd) {
  __shared__ float tile[32][33];
  const float* src = src0 + (size_t)blockIdx.z * srcStride;
  u16* dst = dst0 + (size_t)blockIdx.z * dstStride;
  int tx = threadIdx.x & 31, ty = threadIdx.x >> 5;  // 32 x 8
  int bx = blockIdx.x, by = blockIdx.y;
#pragma unroll
  for (int i = 0; i < 32; i += 8) {
    int r = by * 32 + ty + i, c = bx * 32 + tx;
    tile[ty + i][tx] = src[(size_t)r * C + c];
  }
  __syncthreads();
#pragma unroll
  for (int i = 0; i < 32; i += 8) {
    int c = bx * 32 + ty + i;   // dst logical row (source col)
    int r = by * 32 + tx;       // dst col (source row)
    dst[(size_t)(c * rowMul + rowAdd) * R + r] = f2bf(tile[tx][ty + i]);
  }
}

__global__ void embed_gather_kernel(const int* __restrict__ idx, const float* __restrict__ embed,
                                    float* __restrict__ x) {
  int t = blockIdx.x;
  int id = idx[t];
  ((float4*)x)[(size_t)t * 256 + threadIdx.x] = ((const float4*)embed)[(size_t)id * 256 + threadIdx.x];
}

// x fp32 [4096][1024] -> h bf16, h = x * rsqrt(mean(x^2)+eps) * w
__global__ __launch_bounds__(256) void rmsnorm_kernel(const float* __restrict__ x,
                                                      const float* __restrict__ w,
                                                      u16* __restrict__ h) {
  int row = blockIdx.x;
  const float4* xr = (const float4*)(x + (size_t)row * D_MODEL);
  float4 v = xr[threadIdx.x];
  float ss = v.x * v.x + v.y * v.y + v.z * v.z + v.w * v.w;
#pragma unroll
  for (int m = 32; m > 0; m >>= 1) ss += __shfl_xor(ss, m, 64);
  __shared__ float wsum[4];
  if ((threadIdx.x & 63) == 0) wsum[threadIdx.x >> 6] = ss;
  __syncthreads();
  float tot = wsum[0] + wsum[1] + wsum[2] + wsum[3];
  float rinv = rsqrtf(tot * (1.0f / (float)D_MODEL) + 1e-6f);
  float4 wv = ((const float4*)w)[threadIdx.x];
  u16 out[4];
  out[0] = f2bf(v.x * rinv * wv.x);
  out[1] = f2bf(v.y * rinv * wv.y);
  out[2] = f2bf(v.z * rinv * wv.z);
  out[3] = f2bf(v.w * rinv * wv.w);
  u16* hp = h + (size_t)row * D_MODEL + threadIdx.x * 4;
  hp[0] = out[0]; hp[1] = out[1]; hp[2] = out[2]; hp[3] = out[3];
}

// ---------------- GEMM 256x256, BK=32, 4-deep LDS pipeline (T2+T3+T4+T5) ----------------
// C[M,N] = A[M,K](bf16) * B[N,K](bf16)^T. 512 threads = 8 waves (2M x 4N).
// LDS 128 KiB: 4 K-tile buffers x (A[256x32] + B[256x32]); prefetch depth 3;
// steady-state wait = vmcnt(8) (never 0 until the tail). XOR swizzle chunk^=(row>>2)&3
// on both the global source and the ds_read (2-way aliasing = free).
// EPI: 0 = fp32 store + per-(row,64col) LSE partials; 1 = bf16 store;
//      3 = silu-mul pairing (B rows interleaved gate/up), bf16 store at N/2 width.
template <int EPI>
__global__ __launch_bounds__(512, 2) void gemm256_kernel(const u16* __restrict__ A,
                                                         const u16* __restrict__ B, void* Cp,
                                                         float* __restrict__ partM,
                                                         float* __restrict__ partS,
                                                         int M, int N, int K) {
  __shared__ u16 lds[4][2][256 * 32];   // 128 KiB
  const int tid = threadIdx.x;
  const int lane = tid & 63, wid = tid >> 6;
  const int wm = wid >> 2, wn = wid & 3;          // 2 x 4 wave grid
  const int q = lane >> 4, l15 = lane & 15;
  const int nbn = N >> 8;
  const int cpx = (int)gridDim.x >> 3;
  const int swz = ((int)blockIdx.x & 7) * cpx + ((int)blockIdx.x >> 3);
  const int bm = swz / nbn, bn = swz % nbn;
  const u16* Ab = A + (size_t)bm * 256 * K;
  const u16* Bb = B + (size_t)bn * 256 * K;

  // stage one K-tile (A: 2 insts, B: 2 insts; 4 gload_lds per wave, same order all waves)
  auto stage = [&](int t) {
    const int k0 = t << 5;
    const int buf = t & 3;
#pragma unroll
    for (int inst = 0; inst < 2; inst++) {
      int idx = (inst << 9) + tid;            // 0..1023 16B-chunks
      int row = idx >> 2, ch = idx & 3;
      int sc = (ch ^ ((row >> 2) & 3)) << 3;  // pre-swizzled source col (elems)
      gload_lds16(Ab + (size_t)row * K + k0 + sc, &lds[buf][0][idx * 8]);
    }
#pragma unroll
    for (int inst = 0; inst < 2; inst++) {
      int idx = (inst << 9) + tid;
      int row = idx >> 2, ch = idx & 3;
      int sc = (ch ^ ((row >> 2) & 3)) << 3;
      gload_lds16(Bb + (size_t)row * K + k0 + sc, &lds[buf][1][idx * 8]);
    }
  };

  f32x4 acc[8][4] = {};
  const int NT = K >> 5;   // K-tiles (>= 3 for all call sites)

  stage(0); stage(1); stage(2);   // 12 loads outstanding

  for (int kt = 0; kt < NT; kt++) {
    if (kt < NT - 2)      asm volatile("s_waitcnt vmcnt(8)" ::: "memory");
    else if (kt == NT - 2) asm volatile("s_waitcnt vmcnt(4)" ::: "memory");
    else                   asm volatile("s_waitcnt vmcnt(0)" ::: "memory");
    __builtin_amdgcn_s_barrier();
    asm volatile("" ::: "memory");   // fence: no LDS access hoists above the barrier
    if (kt + 3 < NT) stage(kt + 3);

    const int buf = kt & 3;
    short8 a8[8], b8[4];
#pragma unroll
    for (int mi = 0; mi < 8; mi++) {
      int row = wm * 128 + mi * 16 + l15;
      a8[mi] = *(const short8*)&lds[buf][0][row * 32 + ((q ^ ((row >> 2) & 3)) << 3)];
    }
#pragma unroll
    for (int ni = 0; ni < 4; ni++) {
      int row = wn * 64 + ni * 16 + l15;
      b8[ni] = *(const short8*)&lds[buf][1][row * 32 + ((q ^ ((row >> 2) & 3)) << 3)];
    }
    __builtin_amdgcn_s_setprio(1);
#pragma unroll
    for (int mi = 0; mi < 8; mi++)
#pragma unroll
      for (int ni = 0; ni < 4; ni++)
        acc[mi][ni] = __builtin_amdgcn_mfma_f32_16x16x32_bf16(a8[mi], b8[ni], acc[mi][ni], 0, 0, 0);
    __builtin_amdgcn_s_setprio(0);
  }

  // epilogue
  const int row0 = bm * 256 + wm * 128;
  const int col0 = bn * 256 + wn * 64;
#pragma unroll
  for (int mi = 0; mi < 8; mi++)
#pragma unroll
    for (int j = 0; j < 4; j++) {
      int rr = row0 + mi * 16 + q * 4 + j;
      if (EPI == 0) {
        float mx = -1e30f;
#pragma unroll
        for (int ni = 0; ni < 4; ni++) mx = fmaxf(mx, acc[mi][ni][j]);
        mx = fmaxf(mx, __shfl_xor(mx, 1, 64));
        mx = fmaxf(mx, __shfl_xor(mx, 2, 64));
        mx = fmaxf(mx, __shfl_xor(mx, 4, 64));
        mx = fmaxf(mx, __shfl_xor(mx, 8, 64));
        float sm = 0.f;
#pragma unroll
        for (int ni = 0; ni < 4; ni++) sm += expf(acc[mi][ni][j] - mx);
        sm += __shfl_xor(sm, 1, 64);
        sm += __shfl_xor(sm, 2, 64);
        sm += __shfl_xor(sm, 4, 64);
        sm += __shfl_xor(sm, 8, 64);
        if (l15 == 0) {
          int nt = (N >> 6);
          partM[(size_t)rr * nt + (bn << 2) + wn] = mx;
          partS[(size_t)rr * nt + (bn << 2) + wn] = sm;
        }
      }
#pragma unroll
      for (int ni = 0; ni < 4; ni++) {
        int cn = col0 + ni * 16 + l15;
        float vv = acc[mi][ni][j];
        if (EPI == 0) {
          ((float*)Cp)[(size_t)rr * N + cn] = vv;
        } else if (EPI == 1) {
          ((u16*)Cp)[(size_t)rr * N + cn] = f2bf(vv);
        } else if (EPI == 3) {
          float other = __shfl_xor(vv, 1, 64);
          if ((l15 & 1) == 0) {
            float g = vv, u = other;
            float r = g / (1.0f + expf(-g)) * u;
            ((u16*)Cp)[(size_t)rr * (N >> 1) + (cn >> 1)] = f2bf(r);
          }
        }
      }
    }
}

// ---------------- GEMM 128x128 (m97 structure + both-sides swizzle) ----------------
// EPI: 2 = fp32 residual add (C = resid + acc)
template <int EPI>
__global__ __launch_bounds__(256, 2) void gemm_nt_kernel(const u16* __restrict__ A,
                                                         const u16* __restrict__ B, void* Cp,
                                                         const float* resid, int M, int N, int K) {
  __shared__ u16 As[128 * 64];
  __shared__ u16 Bs[128 * 64];
  const int tid = threadIdx.x;
  const int lane = tid & 63, wid = tid >> 6;
  const int wr = wid >> 1, wc = wid & 1;
  const int nbx = N >> 7;
  const int cpx = gridDim.x >> 3;
  const int swz = (blockIdx.x & 7) * cpx + (blockIdx.x >> 3);
  const int bm = swz / nbx, bn = swz - bm * nbx;
  const size_t abase = (size_t)bm * 128 * K;
  const size_t bbase = (size_t)bn * 128 * K;
  f32x4 acc[4][4] = {};
  for (int k0 = 0; k0 < K; k0 += 64) {
#pragma unroll
    for (int i = 0; i < 4; i++) {
      int idx8 = i * 256 + tid;
      int row = idx8 >> 3, ch = idx8 & 7;
      int sc = (ch ^ (row & 7)) << 3;
      gload_lds16(A + abase + (size_t)row * K + k0 + sc, As + idx8 * 8);
      gload_lds16(B + bbase + (size_t)row * K + k0 + sc, Bs + idx8 * 8);
    }
    __syncthreads();
#pragma unroll
    for (int ks = 0; ks < 2; ks++) {
      short8 af[4], bfr[4];
      int chunk = ks * 4 + (lane >> 4);
#pragma unroll
      for (int mi = 0; mi < 4; mi++) {
        int row = wr * 64 + mi * 16 + (lane & 15);
        af[mi] = *(const short8*)&As[row * 64 + ((chunk ^ (row & 7)) << 3)];
      }
#pragma unroll
      for (int ni = 0; ni < 4; ni++) {
        int row = wc * 64 + ni * 16 + (lane & 15);
        bfr[ni] = *(const short8*)&Bs[row * 64 + ((chunk ^ (row & 7)) << 3)];
      }
#pragma unroll
      for (int mi = 0; mi < 4; mi++)
#pragma unroll
        for (int ni = 0; ni < 4; ni++)
          acc[mi][ni] = __builtin_amdgcn_mfma_f32_16x16x32_bf16(af[mi], bfr[ni], acc[mi][ni], 0, 0, 0);
    }
    __syncthreads();
  }
#pragma unroll
  for (int mi = 0; mi < 4; mi++)
#pragma unroll
    for (int ni = 0; ni < 4; ni++)
#pragma unroll
      for (int j = 0; j < 4; j++) {
        int r = bm * 128 + wr * 64 + mi * 16 + (lane >> 4) * 4 + j;
        int cn = bn * 128 + wc * 64 + ni * 16 + (lane & 15);
        size_t off = (size_t)r * N + cn;
        float vv = acc[mi][ni][j];
        if (EPI == 0) ((float*)Cp)[off] = vv;
        else if (EPI == 1) ((u16*)Cp)[off] = f2bf(vv);
        else ((float*)Cp)[off] = resid[off] + vv;
      }
}

// ---------------- flash attention (RoPE fused for Q and K) ----------------
// q/k/v live in the fused QKV buffer (row stride 3072, offsets 0/1024/2048), PRE-rope.
// grid: (qtile 0..15, bh 0..31), block 256 (4 waves x 32 q-rows)
__global__ __launch_bounds__(256) void attn_kernel(const u16* __restrict__ qkv,
                                                   const float* __restrict__ cosb,
                                                   const float* __restrict__ sinb,
                                                   u16* __restrict__ o) {
  __shared__ u16 Ks[64 * 64];
  __shared__ u16 Vt[64 * 64];
  __shared__ u16 Ps[4][32 * 64];
  const u16* q = qkv;
  const u16* k = qkv + D_MODEL;
  const u16* v = qkv + 2 * D_MODEL;
  const int tid = threadIdx.x, lane = tid & 63, wid = tid >> 6;
  const int qg = lane >> 4, l15 = lane & 15;
  const int qt = blockIdx.x;
  const int bh = blockIdx.y;
  const int b = bh >> 4, h = bh & 15;
  const int tok0 = b * TSEQ;
  const int hoff = h * HDIM;
  const int qrow0 = qt * 128 + wid * 32;

  // load Q fragments and apply RoPE in-register (ks0/ks1 hold the rotation pair)
  short8 aq[2][2];
#pragma unroll
  for (int mi = 0; mi < 2; mi++) {
    int r = qrow0 + mi * 16 + l15;
#pragma unroll
    for (int ks = 0; ks < 2; ks++)
      aq[mi][ks] = *(const short8*)(q + (size_t)(tok0 + r) * QKV_STRIDE + hoff + ks * 32 + qg * 8);
#pragma unroll
    for (int j = 0; j < 8; j++) {
      int fi = qg * 8 + j;
      float cc = cosb[r * 32 + fi], ss = sinb[r * 32 + fi];
      float x1 = bf2f((u16)aq[mi][0][j]), x2 = bf2f((u16)aq[mi][1][j]);
      aq[mi][0][j] = (short)f2bf(x1 * cc - x2 * ss);
      aq[mi][1][j] = (short)f2bf(x2 * cc + x1 * ss);
    }
  }
  f32x4 oacc[2][4] = {};
  float mrow[2][4], lrow[2][4];
#pragma unroll
  for (int mi = 0; mi < 2; mi++)
#pragma unroll
    for (int j = 0; j < 4; j++) { mrow[mi][j] = -1e30f; lrow[mi][j] = 0.f; }

  const int nkt = (qt + 1) * 2;
  for (int kt = 0; kt < nkt; kt++) {
    const int kv0 = kt * 64;
    // stage K [64][64] with fused RoPE (swizzled)
    {
      int rr = tid >> 2;            // 0..63
      int cp = (tid & 3) << 3;      // 0,8,16,24
      int t = kv0 + rr;
      const u16* kr = k + (size_t)(tok0 + t) * QKV_STRIDE + hoff;
      short8 k1 = *(const short8*)(kr + cp);
      short8 k2 = *(const short8*)(kr + cp + 32);
      u16x8 o1, o2;
#pragma unroll
      for (int j = 0; j < 8; j++) {
        float cc = cosb[t * 32 + cp + j], ss = sinb[t * 32 + cp + j];
        float a = bf2f((u16)k1[j]), bb = bf2f((u16)k2[j]);
        o1[j] = f2bf(a * cc - bb * ss);
        o2[j] = f2bf(bb * cc + a * ss);
      }
      int ch1 = cp >> 3, ch2 = ch1 + 4;
      *(u16x8*)&Ks[rr * 64 + ((ch1 ^ (rr & 7)) << 3)] = o1;
      *(u16x8*)&Ks[rr * 64 + ((ch2 ^ (rr & 7)) << 3)] = o2;
    }
    // stage V^T: Vt[d][t] (swizzled)
    {
      int d = tid & 63, t4 = (tid >> 6) * 8;
#pragma unroll
      for (int half = 0; half < 2; half++) {
        int t0 = t4 + half * 32;
        short8 pk;
#pragma unroll
        for (int jj = 0; jj < 8; jj++)
          pk[jj] = (short)v[(size_t)(tok0 + kv0 + t0 + jj) * QKV_STRIDE + hoff + d];
        *(short8*)&Vt[d * 64 + (t0 ^ ((d & 7) << 3))] = pk;
      }
    }
    __syncthreads();
    f32x4 sc[2][4] = {};
#pragma unroll
    for (int ks = 0; ks < 2; ks++) {
      short8 bk[4];
      int chunk = ks * 4 + qg;
#pragma unroll
      for (int ni = 0; ni < 4; ni++) {
        int r = ni * 16 + l15;
        bk[ni] = *(const short8*)&Ks[r * 64 + ((chunk ^ (r & 7)) << 3)];
      }
#pragma unroll
      for (int mi = 0; mi < 2; mi++)
#pragma unroll
        for (int ni = 0; ni < 4; ni++)
          sc[mi][ni] = __builtin_amdgcn_mfma_f32_16x16x32_bf16(aq[mi][ks], bk[ni], sc[mi][ni], 0, 0, 0);
    }
    float pm[2][4];
#pragma unroll
    for (int mi = 0; mi < 2; mi++)
#pragma unroll
      for (int j = 0; j < 4; j++) pm[mi][j] = -1e30f;
#pragma unroll
    for (int mi = 0; mi < 2; mi++)
#pragma unroll
      for (int ni = 0; ni < 4; ni++)
#pragma unroll
        for (int j = 0; j < 4; j++) {
          int rq = qrow0 + mi * 16 + qg * 4 + j;
          int ck = kv0 + ni * 16 + l15;
          float s = sc[mi][ni][j] * 0.125f;
          if (ck > rq) s = -1e30f;
          sc[mi][ni][j] = s;
          pm[mi][j] = fmaxf(pm[mi][j], s);
        }
#pragma unroll
    for (int mi = 0; mi < 2; mi++)
#pragma unroll
      for (int j = 0; j < 4; j++) {
        float t = pm[mi][j];
        t = fmaxf(t, __shfl_xor(t, 1, 64));
        t = fmaxf(t, __shfl_xor(t, 2, 64));
        t = fmaxf(t, __shfl_xor(t, 4, 64));
        t = fmaxf(t, __shfl_xor(t, 8, 64));
        pm[mi][j] = t;
      }
#pragma unroll
    for (int mi = 0; mi < 2; mi++)
#pragma unroll
      for (int j = 0; j < 4; j++) {
        float mn = fmaxf(mrow[mi][j], pm[mi][j]);
        float fac = expf(mrow[mi][j] - mn);
        lrow[mi][j] *= fac;
#pragma unroll
        for (int df = 0; df < 4; df++) oacc[mi][df][j] *= fac;
        mrow[mi][j] = mn;
      }
    float psum[2][4] = {};
#pragma unroll
    for (int mi = 0; mi < 2; mi++)
#pragma unroll
      for (int ni = 0; ni < 4; ni++)
#pragma unroll
        for (int j = 0; j < 4; j++) {
          float p = expf(sc[mi][ni][j] - mrow[mi][j]);
          psum[mi][j] += p;
          int r32 = mi * 16 + qg * 4 + j;
          int cc = ni * 16 + l15;
          Ps[wid][r32 * 64 + (cc ^ ((r32 & 7) << 3))] = f2bf(p);
        }
#pragma unroll
    for (int mi = 0; mi < 2; mi++)
#pragma unroll
      for (int j = 0; j < 4; j++) {
        float t = psum[mi][j];
        t += __shfl_xor(t, 1, 64);
        t += __shfl_xor(t, 2, 64);
        t += __shfl_xor(t, 4, 64);
        t += __shfl_xor(t, 8, 64);
        lrow[mi][j] += t;
      }
#pragma unroll
    for (int kf = 0; kf < 2; kf++) {
      short8 pa[2], bv[4];
      int kcol = kf * 32 + qg * 8;
#pragma unroll
      for (int mi = 0; mi < 2; mi++) {
        int r = mi * 16 + l15;
        pa[mi] = *(const short8*)&Ps[wid][r * 64 + (kcol ^ ((r & 7) << 3))];
      }
#pragma unroll
      for (int df = 0; df < 4; df++) {
        int r = df * 16 + l15;
        bv[df] = *(const short8*)&Vt[r * 64 + (kcol ^ ((r & 7) << 3))];
      }
#pragma unroll
      for (int mi = 0; mi < 2; mi++)
#pragma unroll
        for (int df = 0; df < 4; df++)
          oacc[mi][df] = __builtin_amdgcn_mfma_f32_16x16x32_bf16(pa[mi], bv[df], oacc[mi][df], 0, 0, 0);
    }
    __syncthreads();
  }
#pragma unroll
  for (int mi = 0; mi < 2; mi++)
#pragma unroll
    for (int df = 0; df < 4; df++)
#pragma unroll
      for (int j = 0; j < 4; j++) {
        int r = qrow0 + mi * 16 + qg * 4 + j;
        int d = df * 16 + l15;
        float val = oacc[mi][df][j] / lrow[mi][j];
        o[(size_t)(tok0 + r) * D_MODEL + hoff + d] = f2bf(val);
      }
}

// ---------------- loss ----------------

__global__ void nll_finalize_kernel(const float* __restrict__ partM, const float* __restrict__ partS,
                                    const float* __restrict__ logits, const int* __restrict__ targets,
                                    float* __restrict__ nll) {
  int tok = blockIdx.x;
  int lane = threadIdx.x;    // 64
  const int NTL = V_SIZE >> 6;  // 500
  float m = -1e30f, s = 0.f;
  for (int i = lane; i < NTL; i += 64) {
    float m2 = partM[(size_t)tok * NTL + i];
    float s2 = partS[(size_t)tok * NTL + i];
    float nm = fmaxf(m, m2);
    s = s * expf(m - nm) + s2 * expf(m2 - nm);
    m = nm;
  }
#pragma unroll
  for (int mask = 1; mask < 64; mask <<= 1) {
    float m2 = __shfl_xor(m, mask, 64);
    float s2 = __shfl_xor(s, mask, 64);
    float nm = fmaxf(m, m2);
    s = s * expf(m - nm) + s2 * expf(m2 - nm);
    m = nm;
  }
  if (lane == 0)
    nll[tok] = m + logf(s) - logits[(size_t)tok * V_SIZE + targets[tok]];
}

__global__ void loss_reduce_kernel(const float* __restrict__ nll, float* __restrict__ out) {
  float s = 0.f;
  for (int i = threadIdx.x; i < BT; i += 256) s += nll[i];
#pragma unroll
  for (int mask = 1; mask < 64; mask <<= 1) s += __shfl_xor(s, mask, 64);
  __shared__ float sm[4];
  if ((threadIdx.x & 63) == 0) sm[threadIdx.x >> 6] = s;
  __syncthreads();
  if (threadIdx.x == 0) out[0] = (sm[0] + sm[1] + sm[2] + sm[3]) / (float)BT;
}

// ---------------- host launcher ----------------

extern "C" void kernel_launch(void* const* d_in, const int* in_sizes, int n_in,
                              void* d_out, int out_size, void* d_ws, size_t ws_size,
                              hipStream_t stream) {
  const int* idx = (const int*)d_in[0];
  const int* targets = (const int*)d_in[1];
  const float* embed = (const float*)d_in[2];
  const float* wq = (const float*)d_in[3];
  const float* wk = (const float*)d_in[4];
  const float* wv = (const float*)d_in[5];
  const float* wo = (const float*)d_in[6];
  const float* w_gate = (const float*)d_in[7];
  const float* w_up = (const float*)d_in[8];
  const float* w_down = (const float*)d_in[9];
  const float* attn_norm = (const float*)d_in[10];
  const float* mlp_norm = (const float*)d_in[11];
  const float* final_norm = (const float*)d_in[12];
  const float* lm_head = (const float*)d_in[13];
  float* out = (float*)d_out;

  char* ws = (char*)d_ws;
  size_t off = 0;
  auto alloc = [&](size_t bytes) {
    void* p = ws + off;
    off += (bytes + 255) & ~(size_t)255;
    return p;
  };
  const size_t DD = (size_t)D_MODEL * D_MODEL;
  float* rope_cos = (float*)alloc((size_t)TSEQ * 32 * 4);
  float* rope_sin = (float*)alloc((size_t)TSEQ * 32 * 4);
  float* X = (float*)alloc((size_t)BT * D_MODEL * 4);
  u16* Hb = (u16*)alloc((size_t)BT * D_MODEL * 2);
  u16* QKVb = (u16*)alloc((size_t)BT * QKV_STRIDE * 2);
  u16* Ob = (u16*)alloc((size_t)BT * D_MODEL * 2);
  u16* Gb = (u16*)alloc((size_t)BT * HFF * 2);
  u16* WQKVT = (u16*)alloc((size_t)NLAYER * QKV_STRIDE * D_MODEL * 2);
  u16* WOT = (u16*)alloc((size_t)NLAYER * DD * 2);
  u16* WGU = (u16*)alloc((size_t)NLAYER * GU_STRIDE * D_MODEL * 2);
  u16* WDT = (u16*)alloc((size_t)NLAYER * D_MODEL * HFF * 2);
  u16* LMH = (u16*)alloc((size_t)V_SIZE * D_MODEL * 2);
  float* NLLb = (float*)alloc((size_t)BT * 4);
  float* PartM = (float*)alloc((size_t)BT * (V_SIZE >> 6) * 4);
  float* PartS = (float*)alloc((size_t)BT * (V_SIZE >> 6) * 4);

  rope_table_kernel<<<256, 256, 0, stream>>>(rope_cos, rope_sin);
  convert_bf16_kernel<<<4096, 256, 0, stream>>>(lm_head, LMH, (long)V_SIZE * D_MODEL / 8);
  embed_gather_kernel<<<BT, 256, 0, stream>>>(idx, embed, X);

  const long QKVW = (long)QKV_STRIDE * D_MODEL;
  const long GUW = (long)GU_STRIDE * D_MODEL;
  const long DW = (long)D_MODEL * HFF;
  transpose_bf16_kernel<<<dim3(32, 32, NLAYER), 256, 0, stream>>>(wq, WQKVT, D_MODEL, D_MODEL, DD, QKVW, 1, 0);
  transpose_bf16_kernel<<<dim3(32, 32, NLAYER), 256, 0, stream>>>(wk, WQKVT + DD, D_MODEL, D_MODEL, DD, QKVW, 1, 0);
  transpose_bf16_kernel<<<dim3(32, 32, NLAYER), 256, 0, stream>>>(wv, WQKVT + 2 * DD, D_MODEL, D_MODEL, DD, QKVW, 1, 0);
  transpose_bf16_kernel<<<dim3(32, 32, NLAYER), 256, 0, stream>>>(wo, WOT, D_MODEL, D_MODEL, DD, DD, 1, 0);
  // gate/up interleaved: B row 2j = gate col j, row 2j+1 = up col j
  transpose_bf16_kernel<<<dim3(128, 32, NLAYER), 256, 0, stream>>>(w_gate, WGU, D_MODEL, HFF, DW, GUW, 2, 0);
  transpose_bf16_kernel<<<dim3(128, 32, NLAYER), 256, 0, stream>>>(w_up, WGU, D_MODEL, HFF, DW, GUW, 2, 1);
  transpose_bf16_kernel<<<dim3(32, 128, NLAYER), 256, 0, stream>>>(w_down, WDT, HFF, D_MODEL, DW, DW, 1, 0);

  for (int l = 0; l < NLAYER; l++) {
    rmsnorm_kernel<<<BT, 256, 0, stream>>>(X, attn_norm + (size_t)l * D_MODEL, Hb);
    gemm256_kernel<1><<<(QKV_STRIDE / 256) * (BT / 256), 512, 0, stream>>>(
        Hb, WQKVT + (size_t)l * QKVW, QKVb, nullptr, nullptr, BT, QKV_STRIDE, D_MODEL);
    attn_kernel<<<dim3(16, 32), 256, 0, stream>>>(QKVb, rope_cos, rope_sin, Ob);
    gemm_nt_kernel<2><<<(D_MODEL / 128) * (BT / 128), 256, 0, stream>>>(
        Ob, WOT + (size_t)l * DD, X, X, BT, D_MODEL, D_MODEL);

    rmsnorm_kernel<<<BT, 256, 0, stream>>>(X, mlp_norm + (size_t)l * D_MODEL, Hb);
    gemm256_kernel<3><<<(GU_STRIDE / 256) * (BT / 256), 512, 0, stream>>>(
        Hb, WGU + (size_t)l * GUW, Gb, nullptr, nullptr, BT, GU_STRIDE, D_MODEL);
    gemm_nt_kernel<2><<<(D_MODEL / 128) * (BT / 128), 256, 0, stream>>>(
        Gb, WDT + (size_t)l * DW, X, X, BT, D_MODEL, HFF);
  }

  rmsnorm_kernel<<<BT, 256, 0, stream>>>(X, final_norm, Hb);
  gemm256_kernel<0><<<(V_SIZE / 256) * (BT / 256), 512, 0, stream>>>(
      Hb, LMH, out, PartM, PartS, BT, V_SIZE, D_MODEL);
  nll_finalize_kernel<<<BT, 64, 0, stream>>>(PartM, PartS, out, targets, NLLb);
  loss_reduce_kernel<<<1, 256, 0, stream>>>(NLLb, out + (size_t)BT * V_SIZE);
}